// Round 6
// baseline (268.626 us; speedup 1.0000x reference)
//
#include <hip/hip_runtime.h>

// FTScanBasic: inclusive cumsum along axis 0 of xs[8192][4096] fp32.
// d_out layout: [0..4095] = final carry (ys[-1]), [4096..] = ys flat.
//
// Three-kernel chunked scan. History:
//   r1: fused decoupled-lookback  -> 5x regression (per-block agent fences).
//   r4: cooperative grid.sync fusion -> 139us vs ~77us (device-scope barrier
//       invalidates all L2s). Kernel boundary beats in-kernel barriers.
//   r3: two-pass + nt ys stores = best so far (kernels ~80us of dur 245.3).
//   r5: nt xs loads + reversal = neutral (reverted).
// This version: CHUNKS 128->256 (grid 1024 = 4 blocks/CU, was 2/CU — more
// waves to hide HBM latency per Guideline 11) + tiny in-place exclusive-
// prefix kernel over partials so pass2's prologue is ONE L2 load instead of
// <=255 (removes 133+ MB of L2 prefix traffic and the chunk-imbalanced
// prologue). ys/carry stores stay NONTEMPORAL (keep xs LLC-resident).
// Fallback to the proven r3 two-pass if ws_size < 4 MiB.

constexpr int T_ROWS = 8192;
constexpr int D_COLS = 4096;
constexpr int D4 = D_COLS / 4;            // 1024 float4 per row
constexpr int THREADS = 256;
constexpr int COL_BLOCKS = D4 / THREADS;  // 4

// ---- new path: 256 chunks ----
constexpr int CHUNKS = 256;
constexpr int RPC = T_ROWS / CHUNKS;      // 32 rows per chunk
constexpr size_t WS_NEED = (size_t)CHUNKS * D4 * sizeof(float4);  // 4 MiB

// ---- fallback path: 128 chunks (r3 proven) ----
constexpr int FB_CHUNKS = 128;
constexpr int FB_RPC = T_ROWS / FB_CHUNKS; // 64

typedef float f32x4 __attribute__((ext_vector_type(4)));

__device__ __forceinline__ void acc4(float4& a, const float4& v) {
    a.x += v.x; a.y += v.y; a.z += v.z; a.w += v.w;
}

__device__ __forceinline__ void nt_store4(const float4& v, float4* p) {
    f32x4 w; w.x = v.x; w.y = v.y; w.z = v.z; w.w = v.w;
    __builtin_nontemporal_store(w, reinterpret_cast<f32x4*>(p));
}

// ---------------- new 3-kernel path ----------------
__global__ __launch_bounds__(THREADS)
void scan_pass1(const float4* __restrict__ xs, float4* __restrict__ partials) {
    const int col4  = blockIdx.x * THREADS + threadIdx.x;  // 0..1023
    const int chunk = blockIdx.y;                          // 0..255
    const float4* p = xs + (size_t)chunk * RPC * D4 + col4;
    float4 acc = make_float4(0.f, 0.f, 0.f, 0.f);
#pragma unroll 8
    for (int r = 0; r < RPC; ++r) {
        acc4(acc, p[(size_t)r * D4]);
    }
    partials[(size_t)chunk * D4 + col4] = acc;   // L2-resident, tiny
}

// In-place column-wise exclusive prefix over partials[CHUNKS][D4].
// 4 blocks x 256 threads: thread owns one float4 column, serial over chunks.
__global__ __launch_bounds__(THREADS)
void scan_prefix(float4* __restrict__ partials) {
    const int col4 = blockIdx.x * THREADS + threadIdx.x;   // 0..1023
    float4 run = make_float4(0.f, 0.f, 0.f, 0.f);
#pragma unroll 8
    for (int c = 0; c < CHUNKS; ++c) {
        float4* p = &partials[(size_t)c * D4 + col4];
        float4 v = *p;
        *p = run;            // exclusive prefix in place
        acc4(run, v);
    }
}

__global__ __launch_bounds__(THREADS)
void scan_pass2(const float4* __restrict__ xs, const float4* __restrict__ partials,
                float4* __restrict__ ys, float4* __restrict__ carry) {
    const int col4  = blockIdx.x * THREADS + threadIdx.x;
    const int chunk = blockIdx.y;

    // Exclusive prefix: ONE L2-hot load (precomputed by scan_prefix).
    float4 run = partials[(size_t)chunk * D4 + col4];

    // Stream this chunk: xs reads LLC-hot (parked by pass1), cached;
    // ys writes nontemporal (don't evict xs for still-running blocks).
    const size_t base = (size_t)chunk * RPC * D4 + col4;
#pragma unroll 8
    for (int r = 0; r < RPC; ++r) {
        acc4(run, xs[base + (size_t)r * D4]);
        nt_store4(run, &ys[base + (size_t)r * D4]);
    }

    if (chunk == CHUNKS - 1) {
        nt_store4(run, &carry[col4]);  // ys[-1]
    }
}

// ---------------- fallback: proven r3 two-pass ----------------
__global__ __launch_bounds__(THREADS)
void fb_pass1(const float4* __restrict__ xs, float4* __restrict__ partials) {
    const int col4  = blockIdx.x * THREADS + threadIdx.x;
    const int chunk = blockIdx.y;
    const float4* p = xs + (size_t)chunk * FB_RPC * D4 + col4;
    float4 acc = make_float4(0.f, 0.f, 0.f, 0.f);
#pragma unroll 8
    for (int r = 0; r < FB_RPC; ++r) acc4(acc, p[(size_t)r * D4]);
    partials[(size_t)chunk * D4 + col4] = acc;
}

__global__ __launch_bounds__(THREADS)
void fb_pass2(const float4* __restrict__ xs, const float4* __restrict__ partials,
              float4* __restrict__ ys, float4* __restrict__ carry) {
    const int col4  = blockIdx.x * THREADS + threadIdx.x;
    const int chunk = blockIdx.y;
    float4 run = make_float4(0.f, 0.f, 0.f, 0.f);
#pragma unroll 4
    for (int c = 0; c < chunk; ++c) acc4(run, partials[(size_t)c * D4 + col4]);
    const size_t base = (size_t)chunk * FB_RPC * D4 + col4;
#pragma unroll 8
    for (int r = 0; r < FB_RPC; ++r) {
        acc4(run, xs[base + (size_t)r * D4]);
        nt_store4(run, &ys[base + (size_t)r * D4]);
    }
    if (chunk == FB_CHUNKS - 1) nt_store4(run, &carry[col4]);
}

extern "C" void kernel_launch(void* const* d_in, const int* in_sizes, int n_in,
                              void* d_out, int out_size, void* d_ws, size_t ws_size,
                              hipStream_t stream) {
    const float4* xs = (const float4*)d_in[0];
    float* out = (float*)d_out;
    float4* carry = (float4*)out;                 // first 4096 floats
    float4* ys = (float4*)(out + D_COLS);         // 16 KiB offset, 16B-aligned
    float4* partials = (float4*)d_ws;

    if (ws_size >= WS_NEED) {
        dim3 grid(COL_BLOCKS, CHUNKS);            // 4 x 256 = 1024 blocks
        scan_pass1<<<grid, THREADS, 0, stream>>>(xs, partials);
        scan_prefix<<<dim3(COL_BLOCKS), THREADS, 0, stream>>>(partials);
        scan_pass2<<<grid, THREADS, 0, stream>>>(xs, partials, ys, carry);
    } else {
        dim3 grid(COL_BLOCKS, FB_CHUNKS);         // 4 x 128 = 512 blocks
        fb_pass1<<<grid, THREADS, 0, stream>>>(xs, partials);
        fb_pass2<<<grid, THREADS, 0, stream>>>(xs, partials, ys, carry);
    }
}